// Round 1
// baseline (141.636 us; speedup 1.0000x reference)
//
#include <hip/hip_runtime.h>

// AGMBrain: N=128, B=32, IN_FEAT=4608, grid_size=3, num_candidates=8, n_steps=2
//
// Algebraic reduction:
//   messages[b,d,i] = (sum_j T[b,d,i,j]) * (sum_n s[b,d,n])        (einsum factorizes!)
//   Step 1: s0[b,d,n] = NS[n,d] + t  (t = x_t[b,d] scalar) ->
//     m1[b,d,i] = (colsum[d] + 128 t) * (At[d,i] + t*e[i])
//     At = (EJ @ NS)^T, EJ[i,n] = sum_j E[i,j,n], e[i] = sum_n EJ[i,n]
//   Step 2: only i = 127 survives (out = states[:,:,-1]):
//     out[b,d] = relu( (d!=127) * (sum_i s1_i) * (sum_i EJ[127,i] s1_i) )

#define KQ 1152  // 4608/4

__device__ __forceinline__ float wave_reduce64(float v) {
#pragma unroll
  for (int m = 32; m >= 1; m >>= 1) v += __shfl_xor(v, m);
  return v;
}

// ws float offsets
#define WS_EJ 0        // 16384
#define WS_E 16384     // 128
#define WS_CS 16512    // 128
#define WS_XT 16640    // 4096
#define WS_AT 20736    // 16384
#define WS_OBD 37120   // 4096

// K1: blocks 0..127 -> EJ row i + e[i]; block 128 -> colsum; blocks 129..192 -> x_t (2 d's each)
__global__ __launch_bounds__(256) void k1_pre(const float* __restrict__ ev,
                                              const float* __restrict__ ns,
                                              const float* __restrict__ x,
                                              const float* __restrict__ ipw,
                                              const float* __restrict__ ipb,
                                              float* __restrict__ ws) {
  __shared__ __align__(16) float smem[9216];
  float* EJ = ws + WS_EJ;
  int tid = threadIdx.x;
  int blk = blockIdx.x;
  if (blk < 128) {
    int i = blk;
    int n = tid & 127, jh = tid >> 7;
    const float* Ep = ev + i * 16384 + jh * 8192 + n;
    float acc = 0.f;
#pragma unroll 8
    for (int j = 0; j < 64; ++j) acc += Ep[j * 128];
    smem[tid] = acc;
    __syncthreads();
    float full = 0.f;
    if (tid < 128) {
      full = smem[tid] + smem[tid + 128];
      EJ[i * 128 + tid] = full;
    }
    float r = wave_reduce64(full);  // waves 2,3 contribute 0
    __syncthreads();
    if ((tid & 63) == 0) smem[tid >> 6] = r;
    __syncthreads();
    if (tid == 0) (ws + WS_E)[i] = smem[0] + smem[1] + smem[2] + smem[3];
  } else if (blk == 128) {
    int d = tid & 127, nh = tid >> 7;
    const float* Np = ns + nh * 64 * 128 + d;
    float acc = 0.f;
#pragma unroll 8
    for (int n = 0; n < 64; ++n) acc += Np[n * 128];
    smem[tid] = acc;
    __syncthreads();
    if (tid < 128) (ws + WS_CS)[tid] = smem[tid] + smem[tid + 128];
  } else {
    int d0 = (blk - 129) * 2;
    for (int idx = tid; idx < 9216; idx += 256) smem[idx] = ipw[d0 * 4608 + idx];
    __syncthreads();
    int wv = tid >> 6, lane = tid & 63;
    const float4* x4 = (const float4*)x;
    const float4* w4 = (const float4*)smem;
    float* xt = ws + WS_XT;
    for (int b = wv; b < 32; b += 4) {
      float a0 = 0.f, a1 = 0.f;
      int base = b * KQ;
      for (int kq = lane; kq < KQ; kq += 64) {
        float4 xv = x4[base + kq];
        float4 w0 = w4[kq];
        float4 w1 = w4[KQ + kq];
        a0 += xv.x * w0.x + xv.y * w0.y + xv.z * w0.z + xv.w * w0.w;
        a1 += xv.x * w1.x + xv.y * w1.y + xv.z * w1.z + xv.w * w1.w;
      }
      a0 = wave_reduce64(a0);
      a1 = wave_reduce64(a1);
      if (lane == 0) {
        xt[b * 128 + d0] = a0 + ipb[d0];
        xt[b * 128 + d0 + 1] = a1 + ipb[d0 + 1];
      }
    }
  }
}

// K2: At[d,i] = sum_n EJ[i,n] * NS[n,d]   (written transposed for coalesced K3 reads)
__global__ __launch_bounds__(256) void k2_at(const float* __restrict__ ns,
                                             float* __restrict__ ws) {
  __shared__ float ej[1024];
  const float* EJ = ws + WS_EJ;
  float* At = ws + WS_AT;
  int tid = threadIdx.x;
  int i0 = blockIdx.x * 8;
  for (int idx = tid; idx < 1024; idx += 256) ej[idx] = EJ[i0 * 128 + idx];
  __syncthreads();
  int d = tid & 127, g = tid >> 7;
  float acc[4] = {0.f, 0.f, 0.f, 0.f};
  for (int n = 0; n < 128; ++n) {
    float v = ns[n * 128 + d];
#pragma unroll
    for (int m = 0; m < 4; ++m) acc[m] += ej[(g * 4 + m) * 128 + n] * v;
  }
#pragma unroll
  for (int m = 0; m < 4; ++m) At[d * 128 + i0 + g * 4 + m] = acc[m];
}

// K3: one wave per (b,d): step-1 closed form -> s1 -> step-2 (i=127 only) -> out[b,d]
__global__ __launch_bounds__(512) void k3_steps(float* __restrict__ ws) {
  const float* xt = ws + WS_XT;
  const float* colsum = ws + WS_CS;
  const float* At = ws + WS_AT;
  const float* e = ws + WS_E;
  const float* ej127 = ws + WS_EJ + 127 * 128;
  float* obd = ws + WS_OBD;
  int gw = blockIdx.x * 8 + (threadIdx.x >> 6);
  int b = gw >> 7, d = gw & 127;
  int l = threadIdx.x & 63;
  float t = xt[b * 128 + d];
  float s0s = colsum[d] + 128.f * t;
  float sig = 0.f, y = 0.f;
#pragma unroll
  for (int m = 0; m < 2; ++m) {
    int i = l + (m << 6);
    float v = s0s * (At[d * 128 + i] + t * e[i]);
    v = (i == d) ? 0.f : v;   // mask step 1
    v = fmaxf(v, 0.f);        // relu
    sig += v;
    y += ej127[i] * v;
  }
  sig = wave_reduce64(sig);
  y = wave_reduce64(y);
  if (l == 0) {
    float m2 = sig * y;
    if (d == 127) m2 = 0.f;   // mask step 2 (i=127)
    obd[b * 128 + d] = fmaxf(m2, 0.f);
  }
}

// K4: blocks 0..71: recreation[b,f] = sum_d out[b,d]*rw[f,d] + rb[f]; block 72: scores
__global__ __launch_bounds__(256) void k4_proj(const float* __restrict__ rw,
                                               const float* __restrict__ rb,
                                               const float* __restrict__ sw,
                                               const float* __restrict__ sb,
                                               const float* __restrict__ ws,
                                               float* __restrict__ out) {
  const float* obd = ws + WS_OBD;
  int tid = threadIdx.x;
  int blk = blockIdx.x;
  if (blk < 72) {
    __shared__ __align__(16) float rwlds[64 * 132];
    __shared__ __align__(16) float outT[128 * 32];
    int f0 = blk * 64;
    for (int idx = tid; idx < 8192; idx += 256) {
      int f = idx >> 7, dd = idx & 127;
      rwlds[f * 132 + dd] = rw[f0 * 128 + idx];
    }
    for (int idx = tid; idx < 4096; idx += 256) {
      outT[idx] = obd[(idx & 31) * 128 + (idx >> 5)];  // outT[d*32+b]
    }
    __syncthreads();
    int fg = tid >> 4, bg = tid & 15;
    float acc[4][2];
#pragma unroll
    for (int m = 0; m < 4; ++m) { acc[m][0] = 0.f; acc[m][1] = 0.f; }
    for (int dq = 0; dq < 128; dq += 4) {
      float wv[4][4];
#pragma unroll
      for (int m = 0; m < 4; ++m) {
        float4 w = *(const float4*)&rwlds[(fg * 4 + m) * 132 + dq];
        wv[m][0] = w.x; wv[m][1] = w.y; wv[m][2] = w.z; wv[m][3] = w.w;
      }
      float ov[4][2];
#pragma unroll
      for (int q = 0; q < 4; ++q) {
        float2 o = *(const float2*)&outT[(dq + q) * 32 + bg * 2];
        ov[q][0] = o.x; ov[q][1] = o.y;
      }
#pragma unroll
      for (int m = 0; m < 4; ++m)
#pragma unroll
        for (int q = 0; q < 4; ++q) {
          acc[m][0] += wv[m][q] * ov[q][0];
          acc[m][1] += wv[m][q] * ov[q][1];
        }
    }
#pragma unroll
    for (int m = 0; m < 4; ++m) {
      int f = f0 + fg * 4 + m;
      float bias = rb[f];
      out[(bg * 2 + 0) * 4608 + f] = acc[m][0] + bias;
      out[(bg * 2 + 1) * 4608 + f] = acc[m][1] + bias;
    }
  } else {
    int b = tid >> 3, l8 = tid & 7;
    float acc = 0.f;
    for (int d = l8; d < 128; d += 8) acc += obd[b * 128 + d] * sw[d];
    acc += __shfl_xor(acc, 1);
    acc += __shfl_xor(acc, 2);
    acc += __shfl_xor(acc, 4);
    if (l8 == 0) out[147456 + b] = acc + sb[0];
  }
}

extern "C" void kernel_launch(void* const* d_in, const int* in_sizes, int n_in,
                              void* d_out, int out_size, void* d_ws, size_t ws_size,
                              hipStream_t stream) {
  const float* x   = (const float*)d_in[0];   // (32, 4608)
  const float* ipw = (const float*)d_in[1];   // (128, 4608)
  const float* ipb = (const float*)d_in[2];   // (128,)
  const float* ns  = (const float*)d_in[3];   // (128, 128)
  const float* ev  = (const float*)d_in[4];   // (128, 128, 128)
  const float* rw  = (const float*)d_in[5];   // (4608, 128)
  const float* rb  = (const float*)d_in[6];   // (4608,)
  const float* sw  = (const float*)d_in[7];   // (1, 128)
  const float* sb  = (const float*)d_in[8];   // (1,)
  float* out = (float*)d_out;                 // 147456 recreation + 32 scores
  float* ws = (float*)d_ws;                   // needs >= 41216 floats (~165 KB)

  k1_pre<<<193, 256, 0, stream>>>(ev, ns, x, ipw, ipb, ws);
  k2_at<<<16, 256, 0, stream>>>(ns, ws);
  k3_steps<<<512, 512, 0, stream>>>(ws);
  k4_proj<<<73, 256, 0, stream>>>(rw, rb, sw, sb, ws, out);
}

// Round 2
// 105.712 us; speedup vs baseline: 1.3398x; 1.3398x over previous
//
#include <hip/hip_runtime.h>

// AGMBrain: N=128, B=32, IN_FEAT=4608, grid_size=3, num_candidates=8, n_steps=2
//
// Algebraic reduction (verified round 1):
//   messages[b,d,i] = (sum_j T[b,d,i,j]) * (sum_n s[b,d,n])   (einsum factorizes)
//   Step 1 closed form: m1[b,d,i] = (colsum[d] + 128 t) * (At[d,i] + t*e[i]),
//     t = x_t[b,d], At = (EJ @ NS)^T, EJ[i,n] = sum_j E[i,j,n], e[i] = sum_n EJ[i,n]
//   Step 2 only needs i = 127: out[b,d] = relu((d!=127) * sig * (EJ[127,:]·s1))
//
// Round 2: latency-bound fix — fine-grained grids, deep MLP per thread.

#define KQ 1152  // 4608/4

__device__ __forceinline__ float wave_reduce64(float v) {
#pragma unroll
  for (int m = 32; m >= 1; m >>= 1) v += __shfl_xor(v, m);
  return v;
}

// ws float offsets
#define WS_EJP 0        // 4*128*128 = 65536  (EJ partials, [jc][i][n])
#define WS_E 65536      // 128
#define WS_CS 65664     // 128
#define WS_XT 65792     // 4096
#define WS_AT 69888     // 16384 (d-major: At[d*128+i])
#define WS_EJ127 86272  // 128
#define WS_OBD 86400    // 4096
// total 90496 floats = 362 KB

// K1: blocks 0..511   -> EJ partials: blk = i*4 + jc, sum 32 j's
//     blocks 512..1535 -> x_t: one wave per (b,d) output
//     block 1536       -> colsum[d] = sum_n ns[n,d]
__global__ __launch_bounds__(256) void k1_pre(const float* __restrict__ ev,
                                              const float* __restrict__ ns,
                                              const float* __restrict__ x,
                                              const float* __restrict__ ipw,
                                              const float* __restrict__ ipb,
                                              float* __restrict__ ws) {
  __shared__ __align__(16) float4 sarr[256];
  int tid = threadIdx.x;
  int blk = blockIdx.x;
  if (blk < 512) {
    int i = blk >> 2, jc = blk & 3;
    int n4 = tid & 31, jg = tid >> 5;  // 8 j-groups
    const float4* ev4 = (const float4*)ev;
    float4 acc = make_float4(0.f, 0.f, 0.f, 0.f);
#pragma unroll
    for (int jj = 0; jj < 4; ++jj) {
      int j = jc * 32 + jj * 8 + jg;
      float4 v = ev4[i * 4096 + j * 32 + n4];
      acc.x += v.x; acc.y += v.y; acc.z += v.z; acc.w += v.w;
    }
    sarr[tid] = acc;
    __syncthreads();
    if (tid < 32) {
      float4 s = sarr[tid];
#pragma unroll
      for (int k = 1; k < 8; ++k) {
        float4 v = sarr[tid + 32 * k];
        s.x += v.x; s.y += v.y; s.z += v.z; s.w += v.w;
      }
      ((float4*)(ws + WS_EJP))[(jc * 128 + i) * 32 + tid] = s;
    }
  } else if (blk < 1536) {
    int gw = (blk - 512) * 4 + (tid >> 6);  // 0..4095
    int b = gw >> 7, d = gw & 127, lane = tid & 63;
    const float4* x4 = (const float4*)x;
    const float4* w4 = (const float4*)ipw;
    float acc = 0.f;
#pragma unroll 6
    for (int kq = lane; kq < KQ; kq += 64) {
      float4 xv = x4[b * KQ + kq];
      float4 wv = w4[d * KQ + kq];
      acc += xv.x * wv.x + xv.y * wv.y + xv.z * wv.z + xv.w * wv.w;
    }
    acc = wave_reduce64(acc);
    if (lane == 0) (ws + WS_XT)[b * 128 + d] = acc + ipb[d];
  } else {
    float* smem = (float*)sarr;
    int d = tid & 127, nh = tid >> 7;
    const float* Np = ns + nh * 64 * 128 + d;
    float acc = 0.f;
#pragma unroll 8
    for (int n = 0; n < 64; ++n) acc += Np[n * 128];
    smem[tid] = acc;
    __syncthreads();
    if (tid < 128) (ws + WS_CS)[tid] = smem[tid] + smem[tid + 128];
  }
}

// K2: 64 blocks, 2 i-rows each: reduce EJ partials -> EJ rows (smem),
//     e[i], EJ127 row, and At[d, i] = sum_n EJ[i,n]*NS[n,d].
__global__ __launch_bounds__(256) void k2_at(const float* __restrict__ ns,
                                             float* __restrict__ ws) {
  __shared__ float ej2[256];  // 2 rows x 128
  int tid = threadIdx.x;
  int i0 = blockIdx.x * 2;
  {
    int r = tid >> 7, n = tid & 127;
    const float* EJp = ws + WS_EJP;
    float v = EJp[(0 * 128 + i0 + r) * 128 + n] + EJp[(1 * 128 + i0 + r) * 128 + n] +
              EJp[(2 * 128 + i0 + r) * 128 + n] + EJp[(3 * 128 + i0 + r) * 128 + n];
    ej2[r * 128 + n] = v;
    if (i0 + r == 127) (ws + WS_EJ127)[n] = v;
  }
  __syncthreads();
  // e[i0..i0+1]
  {
    int w = tid >> 6, l = tid & 63;
    if (w < 2) {
      float v = ej2[w * 128 + l] + ej2[w * 128 + 64 + l];
      v = wave_reduce64(v);
      if (l == 0) (ws + WS_E)[i0 + w] = v;
    }
  }
  // At
  int d = tid & 127, g = tid >> 7;
  float acc = 0.f;
#pragma unroll 8
  for (int n = 0; n < 128; ++n) acc += ej2[g * 128 + n] * ns[n * 128 + d];
  (ws + WS_AT)[d * 128 + i0 + g] = acc;
}

// K3: one wave per (b,d): step-1 closed form -> s1 -> step-2 (i=127 only)
__global__ __launch_bounds__(512) void k3_steps(float* __restrict__ ws) {
  const float* xt = ws + WS_XT;
  const float* colsum = ws + WS_CS;
  const float* At = ws + WS_AT;
  const float* e = ws + WS_E;
  const float* ej127 = ws + WS_EJ127;
  float* obd = ws + WS_OBD;
  int gw = blockIdx.x * 8 + (threadIdx.x >> 6);
  int b = gw >> 7, d = gw & 127;
  int l = threadIdx.x & 63;
  float t = xt[b * 128 + d];
  float s0s = colsum[d] + 128.f * t;
  float sig = 0.f, y = 0.f;
#pragma unroll
  for (int m = 0; m < 2; ++m) {
    int i = l + (m << 6);
    float v = s0s * (At[d * 128 + i] + t * e[i]);
    v = (i == d) ? 0.f : v;  // step-1 mask
    v = fmaxf(v, 0.f);       // relu
    sig += v;
    y += ej127[i] * v;
  }
  sig = wave_reduce64(sig);
  y = wave_reduce64(y);
  if (l == 0) {
    float m2 = sig * y;
    if (d == 127) m2 = 0.f;  // step-2 mask (i=127)
    obd[b * 128 + d] = fmaxf(m2, 0.f);
  }
}

// K4: blocks 0..143: recreation tile 32 f x 32 b; block 144: scores
__global__ __launch_bounds__(256) void k4_proj(const float* __restrict__ rw,
                                               const float* __restrict__ rb,
                                               const float* __restrict__ sw,
                                               const float* __restrict__ sb,
                                               const float* __restrict__ ws,
                                               float* __restrict__ out) {
  const float* obd = ws + WS_OBD;
  int tid = threadIdx.x;
  int blk = blockIdx.x;
  if (blk < 144) {
    __shared__ __align__(16) float rwlds[32 * 136];  // stride 136: 2-way max conflict
    __shared__ float obdT[128 * 33];                 // stride 33: conflict-free transpose
    int f0 = blk * 32;
    const float4* rw4 = (const float4*)rw;
#pragma unroll
    for (int it = 0; it < 4; ++it) {
      int q = tid + 256 * it;          // 1024 float4 = 32 f x 32 n4
      int f = q >> 5, n4 = q & 31;
      *(float4*)&rwlds[f * 136 + n4 * 4] = rw4[f0 * 32 + q];
    }
#pragma unroll
    for (int it = 0; it < 16; ++it) {
      int q = tid + 256 * it;          // 4096: b = q>>7, d = q&127 (coalesced read)
      int b = q >> 7, d = q & 127;
      obdT[d * 33 + b] = obd[q];
    }
    __syncthreads();
    int f = tid >> 3, bg = tid & 7;    // 32 f x 8 b-groups, 4 b each
    float acc[4] = {0.f, 0.f, 0.f, 0.f};
#pragma unroll 4
    for (int d = 0; d < 128; ++d) {
      float w = rwlds[f * 136 + d];
#pragma unroll
      for (int k = 0; k < 4; ++k) acc[k] += w * obdT[d * 33 + bg * 4 + k];
    }
    float bias = rb[f0 + f];
#pragma unroll
    for (int k = 0; k < 4; ++k) out[(bg * 4 + k) * 4608 + f0 + f] = acc[k] + bias;
  } else {
    int b = tid >> 3, l8 = tid & 7;
    float acc = 0.f;
    for (int d = l8; d < 128; d += 8) acc += obd[b * 128 + d] * sw[d];
    acc += __shfl_xor(acc, 1);
    acc += __shfl_xor(acc, 2);
    acc += __shfl_xor(acc, 4);
    if (l8 == 0) out[147456 + b] = acc + sb[0];
  }
}

extern "C" void kernel_launch(void* const* d_in, const int* in_sizes, int n_in,
                              void* d_out, int out_size, void* d_ws, size_t ws_size,
                              hipStream_t stream) {
  const float* x   = (const float*)d_in[0];   // (32, 4608)
  const float* ipw = (const float*)d_in[1];   // (128, 4608)
  const float* ipb = (const float*)d_in[2];   // (128,)
  const float* ns  = (const float*)d_in[3];   // (128, 128)
  const float* ev  = (const float*)d_in[4];   // (128, 128, 128)
  const float* rw  = (const float*)d_in[5];   // (4608, 128)
  const float* rb  = (const float*)d_in[6];   // (4608,)
  const float* sw  = (const float*)d_in[7];   // (1, 128)
  const float* sb  = (const float*)d_in[8];   // (1,)
  float* out = (float*)d_out;                 // 147456 recreation + 32 scores
  float* ws = (float*)d_ws;                   // needs >= 90496 floats (~362 KB)

  k1_pre<<<1537, 256, 0, stream>>>(ev, ns, x, ipw, ipb, ws);
  k2_at<<<64, 256, 0, stream>>>(ns, ws);
  k3_steps<<<512, 512, 0, stream>>>(ws);
  k4_proj<<<145, 256, 0, stream>>>(rw, rb, sw, sb, ws, out);
}